// Round 8
// baseline (11629.098 us; speedup 1.0000x reference)
//
#include <hip/hip_runtime.h>

#define BB 32
#define TSRC 12
#define HORZ 12
#define NN 883
#define DD 10
#define HH 64
#define BN (BB*NN)     // 28256
#define BNP 28288      // 64-aligned stride
#define KP 200         // padded MFMA K (t1: 0..95, t2: 96..191, pad ..199)

typedef __attribute__((ext_vector_type(8))) short short8;
typedef __attribute__((ext_vector_type(4))) float f32x4;

static __device__ __forceinline__ float sigmf(float x) { return 1.f/(1.f + __expf(-x)); }
static __device__ __forceinline__ float tanh_fast(float x) {
  float e = __expf(2.f*x);
  return (e - 1.f) / (e + 1.f);
}
static __device__ __forceinline__ unsigned short bf_hi(float f) {
  unsigned int u = __float_as_uint(f);
  return (unsigned short)((u + 0x7fffu + ((u >> 16) & 1u)) >> 16);
}
static __device__ __forceinline__ float bf_f(unsigned short h) {
  return __uint_as_float(((unsigned int)h) << 16);
}

// ---------------- prep: nv1T/nv2T [10][BNP] ----------------
__global__ __launch_bounds__(256) void prep_kernel(
    const float* __restrict__ tidE1, const float* __restrict__ tidE2,
    const float* __restrict__ diwE1, const float* __restrict__ diwE2,
    const float* __restrict__ nodeE,
    const int* __restrict__ tididx, const int* __restrict__ diwidx,
    int t, int tlen,
    float* __restrict__ nv1T, float* __restrict__ nv2T)
{
  int i = blockIdx.x*256 + threadIdx.x;
  if (i >= BN) return;
  int b = i / NN, n = i - b*NN;
  int gi = (b*tlen + t)*NN + n;
  int ti = tididx[gi]*DD, di = diwidx[gi]*DD;
  int nE = n*DD;
#pragma unroll
  for (int d = 0; d < DD; ++d) {
    float E = nodeE[nE+d];
    nv1T[d*BNP+i] = tanh_fast(E * (tidE1[ti+d] * diwE1[di+d]));
    nv2T[d*BNP+i] = tanh_fast(E * (tidE2[ti+d] * diwE2[di+d]));
  }
}

// ------- weight split prep: Wsp [10][2(hi,lo)][NO][KP] bf16 -------
// k-map: kk<96: 0=x(Wrow0), 1..64=h(Wrows1..64), 65=bias, else 0
//        kk>=96: j=kk-96<=64 -> Wrow 65+j (A-part), else 0
__global__ __launch_bounds__(256) void wsplit_kernel(
    const float* __restrict__ W, const float* __restrict__ bias,
    int NO, unsigned short* __restrict__ Wsp)
{
  int i = blockIdx.x*256 + threadIdx.x;
  int total = DD*NO*KP;
  if (i >= total) return;
  int kk = i % KP; int rest = i / KP;
  int o = rest % NO; int d = rest / NO;
  float v = 0.f;
  if (kk < 96) {
    if (kk == 65) v = bias[d*NO + o];
    else if (kk <= 64) v = W[(size_t)(d*130 + kk)*NO + o];
  } else {
    int j = kk - 96;
    if (j <= 64) v = W[(size_t)(d*130 + 65 + j)*NO + o];
  }
  unsigned short hi = bf_hi(v);
  unsigned short lo = bf_hi(v - bf_f(hi));
  Wsp[((size_t)(d*2+0)*NO + o)*KP + kk] = hi;
  Wsp[((size_t)(d*2+1)*NO + o)*KP + kk] = lo;
}

// ------- attn partial: exp(relu(nv1 nv2^T)) @ [x | h] over m-chunk, raw + rowsum -------
__global__ __launch_bounds__(256,3) void attn_kernel(
    const float* __restrict__ nv1T, const float* __restrict__ nv2T,
    const float* __restrict__ xsrc, int xmode, int t, int tlen,
    const float* __restrict__ hsrc,
    float* __restrict__ axP, float* __restrict__ ls)
{
  __shared__ float nv1s[DD][64];
  __shared__ float nv2s[DD][64];
  __shared__ float xt[64][68];
  __shared__ float ps[64][68];
  int b = blockIdx.y;
  int mc = blockIdx.z;
  int r0 = blockIdx.x * 64;
  int tid = threadIdx.x;
  int rg = tid >> 4, cg = tid & 15;
  int base = b*NN;

  for (int idx = tid; idx < DD*64; idx += 256) {
    int d = idx >> 6, r = idx & 63;
    nv1s[d][r] = (r0 + r < NN) ? nv1T[d*BNP + base + r0 + r] : 0.f;
  }

  float acc[4][4] = {};
  float acc5p[4] = {};
  float acclp[4] = {};

  int mstart = mc*448;
  int mend = min(NN, (mc+1)*448);

  for (int m0 = mstart; m0 < mend; m0 += 64) {
    int mv = min(64, NN - m0);
    __syncthreads();
    for (int idx = tid; idx < DD*64; idx += 256) {
      int d = idx >> 6, m = idx & 63;
      nv2s[d][m] = (m0 + m < NN) ? nv2T[d*BNP + base + m0 + m] : 0.f;
    }
    for (int j = 0; j < 17; ++j) {
      int idx = tid + j*256;
      if (idx < 4160) {
        int c = idx >> 6, m = idx & 63, mm = m0 + m;
        float v = 0.f;
        if (mm < NN) {
          if (c == 0) v = (xmode == 0) ? xsrc[(b*tlen+t)*NN + mm] : xsrc[base + mm];
          else        v = hsrc[(c-1)*BNP + base + mm];
        }
        int sc = (c < 64) ? (c ^ ((m & 7) << 3)) : 64;
        xt[m][sc] = v;
      }
    }
    __syncthreads();
    float s[4][4] = {};
#pragma unroll
    for (int d = 0; d < DD; ++d) {
      float4 a4 = *(const float4*)&nv1s[d][rg*4];
      float4 c4 = *(const float4*)&nv2s[d][cg*4];
      const float* ap = (const float*)&a4;
      const float* cp = (const float*)&c4;
#pragma unroll
      for (int j = 0; j < 4; ++j)
#pragma unroll
        for (int jj = 0; jj < 4; ++jj)
          s[j][jj] += ap[j]*cp[jj];
    }
#pragma unroll
    for (int jj = 0; jj < 4; ++jj) {
      int m = cg*4 + jj;
      float xm = xt[m][64];
      float4 pv;
      float* pp = (float*)&pv;
#pragma unroll
      for (int j = 0; j < 4; ++j) {
        float e = (m < mv) ? __expf(fmaxf(s[j][jj], 0.f)) : 0.f;
        pp[j] = e;
        acclp[j] += e;
        acc5p[j] = fmaf(e, xm, acc5p[j]);
      }
      *(float4*)&ps[m][rg*4] = pv;
    }
    __syncthreads();
    int xorc = cg*4;
    const float* psb = &ps[0][rg*4];
#pragma unroll 4
    for (int m8 = 0; m8 < 64; m8 += 4) {
      float4 p[4], x[4];
#pragma unroll
      for (int u = 0; u < 4; ++u) {
        p[u] = *(const float4*)(psb + (m8+u)*68);
        x[u] = *(const float4*)&xt[m8+u][xorc ^ (((m8+u) & 7) << 3)];
      }
#pragma unroll
      for (int u = 0; u < 4; ++u) {
        const float* pp = (const float*)&p[u];
        const float* xp = (const float*)&x[u];
#pragma unroll
        for (int j = 0; j < 4; ++j)
#pragma unroll
          for (int jj = 0; jj < 4; ++jj)
            acc[j][jj] += pp[j]*xp[jj];
      }
    }
  }
#pragma unroll
  for (int off = 1; off <= 8; off <<= 1) {
#pragma unroll
    for (int j = 0; j < 4; ++j) {
      acclp[j] += __shfl_xor(acclp[j], off, 64);
      acc5p[j] += __shfl_xor(acc5p[j], off, 64);
    }
  }
  float* axPp = axP + (size_t)mc*65*BNP;
  float* lsp  = ls + (size_t)mc*BNP;
#pragma unroll
  for (int j = 0; j < 4; ++j) {
    int r = r0 + rg*4 + j;
    if (r < NN) {
#pragma unroll
      for (int jj = 0; jj < 4; ++jj)
        axPp[(cg*4+jj)*BNP + base + r] = acc[j][jj];
      if (cg == 0) {
        axPp[64*BNP + base + r] = acc5p[j];
        lsp[base + r] = acclp[j];
      }
    }
  }
}

// ======= MFMA split-bf16 GEMM core (shared by gate/upd via macro-ish duplication) =======
// XA k-map matches wsplit. t1 = kf 0..2 (k 0..95), t2 = kf 3..5 (k 96..191).
// out = sum_d nv_d*(t1) + nv_d*lsi*t2   (bias is t1 row 65 with A=1)

// ------- gate: grid (442, 2=co-half). M64 x N64 MFMA. zr = sigmoid -------
__global__ __launch_bounds__(256,1) void gate_mfma(
    const float* __restrict__ xsrc, int xmode, int t, int tlen,
    const float* __restrict__ h,
    const float* __restrict__ axP, const float* __restrict__ ls,
    const float* __restrict__ nv1T,
    const unsigned short* __restrict__ Wsp,   // [10][2][128][KP]
    float* __restrict__ zh, float* __restrict__ rbuf)
{
  __shared__ alignas(16) unsigned short XA1[64*KP];
  __shared__ alignas(16) unsigned short XA2[64*KP];
  __shared__ alignas(16) unsigned short WB[2*64*KP];
  __shared__ float nvs[DD][64];
  __shared__ float lsiS[64];
  int n0 = blockIdx.x*64, co0 = blockIdx.y*64;
  int tid = threadIdx.x;
  // ---- build XA (split xg^T) ----
  {
    int m = tid & 63, kgrp = tid >> 6;
    int gm = n0 + m;
    float xv = 0.f;
    if (gm < BN) {
      if (xmode == 0) { int b = gm/NN; xv = xsrc[(b*tlen+t)*NN + (gm - b*NN)]; }
      else xv = xsrc[gm];
    }
    for (int kk = kgrp; kk < KP; kk += 4) {
      float v = 0.f;
      if (kk == 0) v = xv;
      else if (kk <= 64) v = h[(size_t)(kk-1)*BNP + gm];
      else if (kk == 65) v = 1.f;
      else if (kk >= 96 && kk <= 160) {
        int j = kk - 96;
        v = axP[(size_t)j*BNP + gm] + axP[(size_t)(65+j)*BNP + gm];
      }
      unsigned short hi = bf_hi(v);
      unsigned short lo = bf_hi(v - bf_f(hi));
      XA1[m*KP + kk] = hi;
      XA2[m*KP + kk] = lo;
    }
  }
  for (int idx = tid; idx < DD*64; idx += 256)
    nvs[idx>>6][idx&63] = nv1T[(size_t)(idx>>6)*BNP + n0 + (idx&63)];
  if (tid < 64) lsiS[tid] = 1.f/(ls[n0+tid] + ls[BNP+n0+tid]);
  __syncthreads();
  // ---- A-frags in registers ----
  int w = tid >> 6, lane = tid & 63;
  int lm = lane & 15, quad = lane >> 4;
  int mp = w >> 1, np = w & 1;
  short8 A1[2][6], A2[2][6];
  float4 lsir[2];
#pragma unroll
  for (int mt = 0; mt < 2; ++mt) {
    int mrow = mp*32 + mt*16 + lm;
    const unsigned short* a1p = &XA1[mrow*KP + quad*8];
    const unsigned short* a2p = &XA2[mrow*KP + quad*8];
#pragma unroll
    for (int kf = 0; kf < 6; ++kf) {
      A1[mt][kf] = *(const short8*)(a1p + kf*32);
      A2[mt][kf] = *(const short8*)(a2p + kf*32);
    }
    lsir[mt] = *(const float4*)&lsiS[mp*32 + mt*16 + quad*4];
  }
  f32x4 accO[2][2] = {};
  for (int d = 0; d < DD; ++d) {
    __syncthreads();
    {
      const uint4* sh = (const uint4*)(Wsp + ((size_t)(d*2+0)*128 + co0)*KP);
      const uint4* sl = (const uint4*)(Wsp + ((size_t)(d*2+1)*128 + co0)*KP);
      uint4* dh = (uint4*)WB;
      uint4* dl = (uint4*)(WB + 64*KP);
      for (int j = 0; j < 7; ++j) {
        int idx = tid + j*256;
        if (idx < 1600) { dh[idx] = sh[idx]; dl[idx] = sl[idx]; }
      }
    }
    __syncthreads();
    f32x4 t1[2][2] = {}, t2[2][2] = {};
#pragma unroll
    for (int ntl = 0; ntl < 2; ++ntl) {
      int orow = np*32 + ntl*16 + lm;
      const unsigned short* bhp = &WB[orow*KP + quad*8];
      const unsigned short* blp = &WB[64*KP + orow*KP + quad*8];
#pragma unroll
      for (int kf = 0; kf < 6; ++kf) {
        short8 Bh = *(const short8*)(bhp + kf*32);
        short8 Bl = *(const short8*)(blp + kf*32);
#pragma unroll
        for (int mt = 0; mt < 2; ++mt) {
          if (kf < 3) {
            t1[mt][ntl] = __builtin_amdgcn_mfma_f32_16x16x32_bf16(A1[mt][kf], Bh, t1[mt][ntl], 0,0,0);
            t1[mt][ntl] = __builtin_amdgcn_mfma_f32_16x16x32_bf16(A1[mt][kf], Bl, t1[mt][ntl], 0,0,0);
            t1[mt][ntl] = __builtin_amdgcn_mfma_f32_16x16x32_bf16(A2[mt][kf], Bh, t1[mt][ntl], 0,0,0);
          } else {
            t2[mt][ntl] = __builtin_amdgcn_mfma_f32_16x16x32_bf16(A1[mt][kf], Bh, t2[mt][ntl], 0,0,0);
            t2[mt][ntl] = __builtin_amdgcn_mfma_f32_16x16x32_bf16(A1[mt][kf], Bl, t2[mt][ntl], 0,0,0);
            t2[mt][ntl] = __builtin_amdgcn_mfma_f32_16x16x32_bf16(A2[mt][kf], Bh, t2[mt][ntl], 0,0,0);
          }
        }
      }
    }
#pragma unroll
    for (int mt = 0; mt < 2; ++mt) {
      float4 nv4 = *(const float4*)&nvs[d][mp*32 + mt*16 + quad*4];
      const float* nvp = (const float*)&nv4;
      const float* lsp = (const float*)&lsir[mt];
#pragma unroll
      for (int ntl = 0; ntl < 2; ++ntl)
#pragma unroll
        for (int r = 0; r < 4; ++r)
          accO[mt][ntl][r] += nvp[r]*t1[mt][ntl][r] + nvp[r]*lsp[r]*t2[mt][ntl][r];
    }
  }
  // ---- epilogue: transpose via LDS (reuse XA1) for coalesced stores ----
  float* CT = (float*)XA1;   // [64][67]
  __syncthreads();
#pragma unroll
  for (int mt = 0; mt < 2; ++mt)
#pragma unroll
    for (int ntl = 0; ntl < 2; ++ntl)
#pragma unroll
      for (int r = 0; r < 4; ++r)
        CT[(mp*32 + mt*16 + quad*4 + r)*67 + np*32 + ntl*16 + lm] = accO[mt][ntl][r];
  __syncthreads();
  {
    int mm = tid & 63, og = tid >> 6;
    int gm = n0 + mm;
    if (co0 == 0) {
      for (int j = 0; j < 16; ++j) {
        int o = og*16 + j;
        float z = sigmf(CT[mm*67 + o]);
        float hv = h[(size_t)o*BNP + gm];
        zh[(size_t)o*BNP + gm] = z*hv;
      }
    } else {
      for (int j = 0; j < 16; ++j) {
        int o = og*16 + j;
        rbuf[(size_t)o*BNP + gm] = sigmf(CT[mm*67 + o]);
      }
    }
  }
}

// ------- upd: grid (442). M64 x N64 MFMA. h = r*h+(1-r)*tanh; dec: fused proj -------
__global__ __launch_bounds__(256,1) void upd_mfma(
    const float* __restrict__ xsrc, int xmode, int t, int tlen,
    const float* __restrict__ zh,
    const float* __restrict__ axP, const float* __restrict__ ls,
    const float* __restrict__ nv1T,
    const unsigned short* __restrict__ Wsp,   // [10][2][64][KP]
    const float* __restrict__ rbuf, float* __restrict__ h,
    int dec, const float* __restrict__ pW, const float* __restrict__ pb,
    float* __restrict__ go, float* __restrict__ dout)
{
  __shared__ alignas(16) unsigned short XA1[64*KP];
  __shared__ alignas(16) unsigned short XA2[64*KP];
  __shared__ alignas(16) unsigned short WB[2*64*KP];
  __shared__ float nvs[DD][64];
  __shared__ float lsiS[64];
  int n0 = blockIdx.x*64;
  int tid = threadIdx.x;
  {
    int m = tid & 63, kgrp = tid >> 6;
    int gm = n0 + m;
    float xv = 0.f;
    if (gm < BN) {
      if (xmode == 0) { int b = gm/NN; xv = xsrc[(b*tlen+t)*NN + (gm - b*NN)]; }
      else xv = xsrc[gm];
    }
    for (int kk = kgrp; kk < KP; kk += 4) {
      float v = 0.f;
      if (kk == 0) v = xv;
      else if (kk <= 64) v = zh[(size_t)(kk-1)*BNP + gm];
      else if (kk == 65) v = 1.f;
      else if (kk >= 96 && kk <= 160) {
        int j = kk - 96;
        v = axP[(size_t)j*BNP + gm] + axP[(size_t)(65+j)*BNP + gm];
      }
      unsigned short hi = bf_hi(v);
      unsigned short lo = bf_hi(v - bf_f(hi));
      XA1[m*KP + kk] = hi;
      XA2[m*KP + kk] = lo;
    }
  }
  for (int idx = tid; idx < DD*64; idx += 256)
    nvs[idx>>6][idx&63] = nv1T[(size_t)(idx>>6)*BNP + n0 + (idx&63)];
  if (tid < 64) lsiS[tid] = 1.f/(ls[n0+tid] + ls[BNP+n0+tid]);
  __syncthreads();
  int w = tid >> 6, lane = tid & 63;
  int lm = lane & 15, quad = lane >> 4;
  int mp = w >> 1, np = w & 1;
  short8 A1[2][6], A2[2][6];
  float4 lsir[2];
#pragma unroll
  for (int mt = 0; mt < 2; ++mt) {
    int mrow = mp*32 + mt*16 + lm;
    const unsigned short* a1p = &XA1[mrow*KP + quad*8];
    const unsigned short* a2p = &XA2[mrow*KP + quad*8];
#pragma unroll
    for (int kf = 0; kf < 6; ++kf) {
      A1[mt][kf] = *(const short8*)(a1p + kf*32);
      A2[mt][kf] = *(const short8*)(a2p + kf*32);
    }
    lsir[mt] = *(const float4*)&lsiS[mp*32 + mt*16 + quad*4];
  }
  f32x4 accO[2][2] = {};
  for (int d = 0; d < DD; ++d) {
    __syncthreads();
    {
      const uint4* sh = (const uint4*)(Wsp + (size_t)(d*2+0)*64*KP);
      const uint4* sl = (const uint4*)(Wsp + (size_t)(d*2+1)*64*KP);
      uint4* dh = (uint4*)WB;
      uint4* dl = (uint4*)(WB + 64*KP);
      for (int j = 0; j < 7; ++j) {
        int idx = tid + j*256;
        if (idx < 1600) { dh[idx] = sh[idx]; dl[idx] = sl[idx]; }
      }
    }
    __syncthreads();
    f32x4 t1[2][2] = {}, t2[2][2] = {};
#pragma unroll
    for (int ntl = 0; ntl < 2; ++ntl) {
      int orow = np*32 + ntl*16 + lm;
      const unsigned short* bhp = &WB[orow*KP + quad*8];
      const unsigned short* blp = &WB[64*KP + orow*KP + quad*8];
#pragma unroll
      for (int kf = 0; kf < 6; ++kf) {
        short8 Bh = *(const short8*)(bhp + kf*32);
        short8 Bl = *(const short8*)(blp + kf*32);
#pragma unroll
        for (int mt = 0; mt < 2; ++mt) {
          if (kf < 3) {
            t1[mt][ntl] = __builtin_amdgcn_mfma_f32_16x16x32_bf16(A1[mt][kf], Bh, t1[mt][ntl], 0,0,0);
            t1[mt][ntl] = __builtin_amdgcn_mfma_f32_16x16x32_bf16(A1[mt][kf], Bl, t1[mt][ntl], 0,0,0);
            t1[mt][ntl] = __builtin_amdgcn_mfma_f32_16x16x32_bf16(A2[mt][kf], Bh, t1[mt][ntl], 0,0,0);
          } else {
            t2[mt][ntl] = __builtin_amdgcn_mfma_f32_16x16x32_bf16(A1[mt][kf], Bh, t2[mt][ntl], 0,0,0);
            t2[mt][ntl] = __builtin_amdgcn_mfma_f32_16x16x32_bf16(A1[mt][kf], Bl, t2[mt][ntl], 0,0,0);
            t2[mt][ntl] = __builtin_amdgcn_mfma_f32_16x16x32_bf16(A2[mt][kf], Bh, t2[mt][ntl], 0,0,0);
          }
        }
      }
    }
#pragma unroll
    for (int mt = 0; mt < 2; ++mt) {
      float4 nv4 = *(const float4*)&nvs[d][mp*32 + mt*16 + quad*4];
      const float* nvp = (const float*)&nv4;
      const float* lsp = (const float*)&lsir[mt];
#pragma unroll
      for (int ntl = 0; ntl < 2; ++ntl)
#pragma unroll
        for (int r = 0; r < 4; ++r)
          accO[mt][ntl][r] += nvp[r]*t1[mt][ntl][r] + nvp[r]*lsp[r]*t2[mt][ntl][r];
    }
  }
  float* CT = (float*)XA1;   // [64][67], then PS at +64*67
  __syncthreads();
#pragma unroll
  for (int mt = 0; mt < 2; ++mt)
#pragma unroll
    for (int ntl = 0; ntl < 2; ++ntl)
#pragma unroll
      for (int r = 0; r < 4; ++r)
        CT[(mp*32 + mt*16 + quad*4 + r)*67 + np*32 + ntl*16 + lm] = accO[mt][ntl][r];
  __syncthreads();
  {
    int mm = tid & 63, og = tid >> 6;
    int gm = n0 + mm;
    float pp = 0.f;
    for (int j = 0; j < 16; ++j) {
      int o = og*16 + j;
      float hc = tanhf(CT[mm*67 + o]);
      float r = rbuf[(size_t)o*BNP + gm];
      float hv = h[(size_t)o*BNP + gm];
      float hn = r*hv + (1.f - r)*hc;
      h[(size_t)o*BNP + gm] = hn;
      if (dec) pp = fmaf(hn, pW[o], pp);
    }
    if (dec) {
      float* PS = CT + 64*67;
      __syncthreads();
      PS[mm*4 + og] = pp;
      __syncthreads();
      if (tid < 64 && gm < BN) {
        float s = pb[0] + PS[tid*4] + PS[tid*4+1] + PS[tid*4+2] + PS[tid*4+3];
        go[gm] = s;
        int b = gm/NN, n = gm - b*NN;
        dout[(b*HORZ + t)*NN + n] = s;
      }
    }
  }
}

extern "C" void kernel_launch(void* const* d_in, const int* in_sizes, int n_in,
                              void* d_out, int out_size, void* d_ws, size_t ws_size,
                              hipStream_t stream) {
  (void)in_sizes; (void)n_in; (void)out_size; (void)ws_size;
  const float* src_vals = (const float*)d_in[0];
  const float* node_emb = (const float*)d_in[1];
  const float* tid1 = (const float*)d_in[2];
  const float* tid2 = (const float*)d_in[3];
  const float* diw1 = (const float*)d_in[4];
  const float* diw2 = (const float*)d_in[5];
  const float* egW = (const float*)d_in[6];
  const float* egb = (const float*)d_in[7];
  const float* euW = (const float*)d_in[8];
  const float* eub = (const float*)d_in[9];
  const float* dgW = (const float*)d_in[10];
  const float* dgb = (const float*)d_in[11];
  const float* duW = (const float*)d_in[12];
  const float* dub = (const float*)d_in[13];
  const float* pW  = (const float*)d_in[14];
  const float* pb  = (const float*)d_in[15];
  const int* stid = (const int*)d_in[16];
  const int* sdiw = (const int*)d_in[17];
  const int* ttid = (const int*)d_in[18];
  const int* tdiw = (const int*)d_in[19];
  float* out = (float*)d_out;

  float* wp = (float*)d_ws;
  float* hbuf = wp; wp += (size_t)64*BNP;
  float* zh   = wp; wp += (size_t)64*BNP;
  float* rbuf = wp; wp += (size_t)64*BNP;
  float* axP  = wp; wp += (size_t)2*65*BNP;
  float* ls   = wp; wp += (size_t)2*BNP;
  float* nv1T = wp; wp += (size_t)DD*BNP;
  float* nv2T = wp; wp += (size_t)DD*BNP;
  float* go   = wp; wp += BN;
  unsigned short* egS = (unsigned short*)wp; wp += 256000;  // 10*2*128*200 ushort
  unsigned short* dgS = (unsigned short*)wp; wp += 256000;
  unsigned short* euS = (unsigned short*)wp; wp += 128000;  // 10*2*64*200 ushort
  unsigned short* duS = (unsigned short*)wp; wp += 128000;

  hipMemsetAsync(hbuf, 0, sizeof(float)*(size_t)64*BNP, stream);
  hipMemsetAsync(go, 0, sizeof(float)*BN, stream);

  wsplit_kernel<<<1000,256,0,stream>>>(egW, egb, 128, egS);
  wsplit_kernel<<<1000,256,0,stream>>>(dgW, dgb, 128, dgS);
  wsplit_kernel<<<500,256,0,stream>>>(euW, eub, 64, euS);
  wsplit_kernel<<<500,256,0,stream>>>(duW, dub, 64, duS);

  dim3 agrid(14, BB, 2);
  dim3 ggrid(442, 2);
  for (int t = 0; t < TSRC; ++t) {
    prep_kernel<<<111,256,0,stream>>>(tid1,tid2,diw1,diw2,node_emb,stid,sdiw,t,TSRC,nv1T,nv2T);
    attn_kernel<<<agrid,256,0,stream>>>(nv1T,nv2T,src_vals,0,t,TSRC,hbuf,axP,ls);
    gate_mfma<<<ggrid,256,0,stream>>>(src_vals,0,t,TSRC,hbuf,axP,ls,nv1T,egS,zh,rbuf);
    attn_kernel<<<agrid,256,0,stream>>>(nv1T,nv2T,src_vals,0,t,TSRC,zh,axP,ls);
    upd_mfma<<<442,256,0,stream>>>(src_vals,0,t,TSRC,zh,axP,ls,nv1T,euS,rbuf,hbuf,0,pW,pb,go,out);
  }
  for (int t = 0; t < HORZ; ++t) {
    prep_kernel<<<111,256,0,stream>>>(tid1,tid2,diw1,diw2,node_emb,ttid,tdiw,t,HORZ,nv1T,nv2T);
    attn_kernel<<<agrid,256,0,stream>>>(nv1T,nv2T,go,1,t,HORZ,hbuf,axP,ls);
    gate_mfma<<<ggrid,256,0,stream>>>(go,1,t,HORZ,hbuf,axP,ls,nv1T,dgS,zh,rbuf);
    attn_kernel<<<agrid,256,0,stream>>>(nv1T,nv2T,go,1,t,HORZ,zh,axP,ls);
    upd_mfma<<<442,256,0,stream>>>(go,1,t,HORZ,zh,axP,ls,nv1T,duS,rbuf,hbuf,1,pW,pb,go,out);
  }
}

// Round 9
// 9654.633 us; speedup vs baseline: 1.2045x; 1.2045x over previous
//
#include <hip/hip_runtime.h>

#define BB 32
#define TSRC 12
#define HORZ 12
#define NN 883
#define DD 10
#define HH 64
#define BN (BB*NN)     // 28256
#define BNP 28288      // 64-aligned stride
#define KF 5           // MFMA K-frags: K = 160. k-map: 0=x, 1..64=h, 65=bias, 66..130=attn*lsi, 131..159=0

typedef __attribute__((ext_vector_type(8))) short short8;
typedef __attribute__((ext_vector_type(4))) float f32x4;

static __device__ __forceinline__ float sigmf(float x) { return 1.f/(1.f + __expf(-x)); }
static __device__ __forceinline__ float tanh_fast(float x) {
  float e = __expf(2.f*x);
  return (e - 1.f) / (e + 1.f);
}
static __device__ __forceinline__ unsigned int bf_hi(float f) {
  unsigned int u = __float_as_uint(f);
  return (u + 0x7fffu + ((u >> 16) & 1u)) >> 16;
}
static __device__ __forceinline__ float bf_f(unsigned int h) {
  return __uint_as_float(h << 16);
}

// ---------------- prep: nv1T/nv2T [10][BNP] ----------------
__global__ __launch_bounds__(256) void prep_kernel(
    const float* __restrict__ tidE1, const float* __restrict__ tidE2,
    const float* __restrict__ diwE1, const float* __restrict__ diwE2,
    const float* __restrict__ nodeE,
    const int* __restrict__ tididx, const int* __restrict__ diwidx,
    int t, int tlen,
    float* __restrict__ nv1T, float* __restrict__ nv2T)
{
  int i = blockIdx.x*256 + threadIdx.x;
  if (i >= BN) return;
  int b = i / NN, n = i - b*NN;
  int gi = (b*tlen + t)*NN + n;
  int ti = tididx[gi]*DD, di = diwidx[gi]*DD;
  int nE = n*DD;
#pragma unroll
  for (int d = 0; d < DD; ++d) {
    float E = nodeE[nE+d];
    nv1T[d*BNP+i] = tanh_fast(E * (tidE1[ti+d] * diwE1[di+d]));
    nv2T[d*BNP+i] = tanh_fast(E * (tidE2[ti+d] * diwE2[di+d]));
  }
}

// ------- wsplit: W -> B-fragment-ordered split-bf16 Wf[d][hl][kf][quad][NO][8] -------
__global__ __launch_bounds__(256) void wsplit_kernel(
    const float* __restrict__ W, const float* __restrict__ bias,
    int NO, unsigned short* __restrict__ Wf)
{
  int i = blockIdx.x*256 + threadIdx.x;
  int total = DD*2*KF*4*NO*8;
  if (i >= total) return;
  int j = i & 7; int r = i >> 3;
  int o = r % NO; r /= NO;
  int quad = r & 3; r >>= 2;
  int kf = r % KF; r /= KF;
  int hl = r & 1; int d = r >> 1;
  int kk = kf*32 + quad*8 + j;
  float v = 0.f;
  if (kk <= 64)       v = W[(size_t)(d*130 + kk)*NO + o];       // kk=0 -> x row, 1..64 -> h rows
  else if (kk == 65)  v = bias[d*NO + o];
  else if (kk <= 130) v = W[(size_t)(d*130 + kk - 1)*NO + o];   // attn rows 65..129
  unsigned int hi = bf_hi(v);
  Wf[i] = (hl == 0) ? (unsigned short)hi : (unsigned short)bf_hi(v - bf_f(hi));
}

// ------- attn partial: exp(relu(nv1 nv2^T)) @ [x | h] over m-chunk, raw + rowsum -------
__global__ __launch_bounds__(256,3) void attn_kernel(
    const float* __restrict__ nv1T, const float* __restrict__ nv2T,
    const float* __restrict__ xsrc, int xmode, int t, int tlen,
    const float* __restrict__ hsrc,
    float* __restrict__ axP, float* __restrict__ ls)
{
  __shared__ float nv1s[DD][64];
  __shared__ float nv2s[DD][64];
  __shared__ float xt[64][68];
  __shared__ float ps[64][68];
  int b = blockIdx.y;
  int mc = blockIdx.z;
  int r0 = blockIdx.x * 64;
  int tid = threadIdx.x;
  int rg = tid >> 4, cg = tid & 15;
  int base = b*NN;

  for (int idx = tid; idx < DD*64; idx += 256) {
    int d = idx >> 6, r = idx & 63;
    nv1s[d][r] = (r0 + r < NN) ? nv1T[d*BNP + base + r0 + r] : 0.f;
  }

  float acc[4][4] = {};
  float acc5p[4] = {};
  float acclp[4] = {};

  int mstart = mc*448;
  int mend = min(NN, (mc+1)*448);

  for (int m0 = mstart; m0 < mend; m0 += 64) {
    int mv = min(64, NN - m0);
    __syncthreads();
    for (int idx = tid; idx < DD*64; idx += 256) {
      int d = idx >> 6, m = idx & 63;
      nv2s[d][m] = (m0 + m < NN) ? nv2T[d*BNP + base + m0 + m] : 0.f;
    }
    for (int j = 0; j < 17; ++j) {
      int idx = tid + j*256;
      if (idx < 4160) {
        int c = idx >> 6, m = idx & 63, mm = m0 + m;
        float v = 0.f;
        if (mm < NN) {
          if (c == 0) v = (xmode == 0) ? xsrc[(b*tlen+t)*NN + mm] : xsrc[base + mm];
          else        v = hsrc[(c-1)*BNP + base + mm];
        }
        int sc = (c < 64) ? (c ^ ((m & 7) << 3)) : 64;
        xt[m][sc] = v;
      }
    }
    __syncthreads();
    float s[4][4] = {};
#pragma unroll
    for (int d = 0; d < DD; ++d) {
      float4 a4 = *(const float4*)&nv1s[d][rg*4];
      float4 c4 = *(const float4*)&nv2s[d][cg*4];
      const float* ap = (const float*)&a4;
      const float* cp = (const float*)&c4;
#pragma unroll
      for (int j = 0; j < 4; ++j)
#pragma unroll
        for (int jj = 0; jj < 4; ++jj)
          s[j][jj] += ap[j]*cp[jj];
    }
#pragma unroll
    for (int jj = 0; jj < 4; ++jj) {
      int m = cg*4 + jj;
      float xm = xt[m][64];
      float4 pv;
      float* pp = (float*)&pv;
#pragma unroll
      for (int j = 0; j < 4; ++j) {
        float e = (m < mv) ? __expf(fmaxf(s[j][jj], 0.f)) : 0.f;
        pp[j] = e;
        acclp[j] += e;
        acc5p[j] = fmaf(e, xm, acc5p[j]);
      }
      *(float4*)&ps[m][rg*4] = pv;
    }
    __syncthreads();
    int xorc = cg*4;
    const float* psb = &ps[0][rg*4];
#pragma unroll 4
    for (int m8 = 0; m8 < 64; m8 += 4) {
      float4 p[4], x[4];
#pragma unroll
      for (int u = 0; u < 4; ++u) {
        p[u] = *(const float4*)(psb + (m8+u)*68);
        x[u] = *(const float4*)&xt[m8+u][xorc ^ (((m8+u) & 7) << 3)];
      }
#pragma unroll
      for (int u = 0; u < 4; ++u) {
        const float* pp = (const float*)&p[u];
        const float* xp = (const float*)&x[u];
#pragma unroll
        for (int j = 0; j < 4; ++j)
#pragma unroll
          for (int jj = 0; jj < 4; ++jj)
            acc[j][jj] += pp[j]*xp[jj];
      }
    }
  }
#pragma unroll
  for (int off = 1; off <= 8; off <<= 1) {
#pragma unroll
    for (int j = 0; j < 4; ++j) {
      acclp[j] += __shfl_xor(acclp[j], off, 64);
      acc5p[j] += __shfl_xor(acc5p[j], off, 64);
    }
  }
  float* axPp = axP + (size_t)mc*65*BNP;
  float* lsp  = ls + (size_t)mc*BNP;
#pragma unroll
  for (int j = 0; j < 4; ++j) {
    int r = r0 + rg*4 + j;
    if (r < NN) {
#pragma unroll
      for (int jj = 0; jj < 4; ++jj)
        axPp[(cg*4+jj)*BNP + base + r] = acc[j][jj];
      if (cg == 0) {
        axPp[64*BNP + base + r] = acc5p[j];
        lsp[base + r] = acclp[j];
      }
    }
  }
}

// ======= MFMA GEMM kernels: XA frag-layout LDS, B-frags direct from global =======
// XA row stride = 40 shorts (80B): frag read = ds_read_b128, 2-way banks (free).

// ------- gate: grid (442, 2=co-half). zr = sigmoid -------
__global__ __launch_bounds__(256,2) void gate_mfma(
    const float* __restrict__ xsrc, int xmode, int t, int tlen,
    const float* __restrict__ h,
    const float* __restrict__ axP, const float* __restrict__ ls,
    const float* __restrict__ nv1T,
    const unsigned short* __restrict__ Wf,   // [10][2][KF][4][128][8]
    float* __restrict__ zh, float* __restrict__ rbuf)
{
  __shared__ alignas(16) unsigned short XA1f[KF*64*40];
  __shared__ alignas(16) unsigned short XA2f[KF*64*40];
  __shared__ float nvs[DD][64];
  int n0 = blockIdx.x*64, co0 = blockIdx.y*64;
  int tid = threadIdx.x;
  // ---- build XA: thread (m = tid>>2, ksub = tid&3) handles kk pairs ----
  {
    int m = tid >> 2, ksub = tid & 3;
    int gm = n0 + m;
    float lsi = 1.f/(ls[gm] + ls[BNP+gm]);
    float xv;
    if (xmode == 0) { int b = gm/NN; int n = gm - b*NN; xv = (gm < BN) ? xsrc[(b*tlen+t)*NN + n] : 0.f; }
    else xv = xsrc[gm];
    unsigned int* X1 = (unsigned int*)XA1f;
    unsigned int* X2 = (unsigned int*)XA2f;
#pragma unroll 4
    for (int i = 0; i < 20; ++i) {
      int kk = ksub*2 + 8*i;
      float v0, v1;
      // v for kk and kk+1
      if (kk == 0)        v0 = xv;
      else if (kk <= 64)  v0 = h[(size_t)(kk-1)*BNP + gm];
      else if (kk == 65)  v0 = 1.f;
      else if (kk <= 130) v0 = (axP[(size_t)(kk-66)*BNP + gm] + axP[(size_t)(65+kk-66)*BNP + gm]) * lsi;
      else v0 = 0.f;
      int k1 = kk + 1;
      if (k1 <= 64)       v1 = h[(size_t)(k1-1)*BNP + gm];
      else if (k1 == 65)  v1 = 1.f;
      else if (k1 <= 130) v1 = (axP[(size_t)(k1-66)*BNP + gm] + axP[(size_t)(65+k1-66)*BNP + gm]) * lsi;
      else v1 = 0.f;
      unsigned int h0 = bf_hi(v0), h1 = bf_hi(v1);
      unsigned int l0 = bf_hi(v0 - bf_f(h0)), l1 = bf_hi(v1 - bf_f(h1));
      int kf = kk >> 5, kkl = kk & 31;
      int dw = (kf*64 + m)*20 + (kkl >> 1);
      X1[dw] = h0 | (h1 << 16);
      X2[dw] = l0 | (l1 << 16);
    }
  }
  for (int idx = tid; idx < DD*64; idx += 256)
    nvs[idx>>6][idx&63] = nv1T[(size_t)(idx>>6)*BNP + n0 + (idx&63)];
  __syncthreads();
  // ---- A-frags ----
  int w = tid >> 6, lane = tid & 63;
  int lm = lane & 15, quad = lane >> 4;
  int mp = w >> 1, np = w & 1;
  short8 A1[2][KF], A2[2][KF];
#pragma unroll
  for (int mt = 0; mt < 2; ++mt) {
    int mrow = mp*32 + mt*16 + lm;
#pragma unroll
    for (int kf = 0; kf < KF; ++kf) {
      A1[mt][kf] = *(const short8*)&XA1f[(kf*64 + mrow)*40 + quad*8];
      A2[mt][kf] = *(const short8*)&XA2f[(kf*64 + mrow)*40 + quad*8];
    }
  }
  f32x4 accO[2][2] = {};
  int ob0 = co0 + np*32 + lm;
#pragma unroll 2
  for (int d = 0; d < DD; ++d) {
    f32x4 td[2][2] = {};
#pragma unroll
    for (int ntl = 0; ntl < 2; ++ntl) {
      int ob = ob0 + ntl*16;
#pragma unroll
      for (int kf = 0; kf < KF; ++kf) {
        short8 Bh = *(const short8*)(Wf + ((((size_t)(d*2+0)*KF + kf)*4 + quad)*128 + ob)*8);
        short8 Bl = *(const short8*)(Wf + ((((size_t)(d*2+1)*KF + kf)*4 + quad)*128 + ob)*8);
#pragma unroll
        for (int mt = 0; mt < 2; ++mt) {
          td[mt][ntl] = __builtin_amdgcn_mfma_f32_16x16x32_bf16(A1[mt][kf], Bh, td[mt][ntl], 0,0,0);
          td[mt][ntl] = __builtin_amdgcn_mfma_f32_16x16x32_bf16(A1[mt][kf], Bl, td[mt][ntl], 0,0,0);
          td[mt][ntl] = __builtin_amdgcn_mfma_f32_16x16x32_bf16(A2[mt][kf], Bh, td[mt][ntl], 0,0,0);
        }
      }
    }
#pragma unroll
    for (int mt = 0; mt < 2; ++mt) {
      float4 nv4 = *(const float4*)&nvs[d][mp*32 + mt*16 + quad*4];
      const float* nvp = (const float*)&nv4;
#pragma unroll
      for (int ntl = 0; ntl < 2; ++ntl)
#pragma unroll
        for (int r = 0; r < 4; ++r)
          accO[mt][ntl][r] += nvp[r] * td[mt][ntl][r];
    }
  }
  // ---- epilogue ----
  float* CT = (float*)XA1f;   // [64][67]
  __syncthreads();
#pragma unroll
  for (int mt = 0; mt < 2; ++mt)
#pragma unroll
    for (int ntl = 0; ntl < 2; ++ntl)
#pragma unroll
      for (int r = 0; r < 4; ++r)
        CT[(mp*32 + mt*16 + quad*4 + r)*67 + np*32 + ntl*16 + lm] = accO[mt][ntl][r];
  __syncthreads();
  {
    int mm = tid & 63, og = tid >> 6;
    int gm = n0 + mm;
    if (co0 == 0) {
      for (int j = 0; j < 16; ++j) {
        int o = og*16 + j;
        float z = sigmf(CT[mm*67 + o]);
        zh[(size_t)o*BNP + gm] = z * h[(size_t)o*BNP + gm];
      }
    } else {
      for (int j = 0; j < 16; ++j) {
        int o = og*16 + j;
        rbuf[(size_t)o*BNP + gm] = sigmf(CT[mm*67 + o]);
      }
    }
  }
}

// ------- upd: grid (442). h = r*h+(1-r)*tanh; dec: fused proj -------
__global__ __launch_bounds__(256,2) void upd_mfma(
    const float* __restrict__ xsrc, int xmode, int t, int tlen,
    const float* __restrict__ zh,
    const float* __restrict__ axP, const float* __restrict__ ls,
    const float* __restrict__ nv1T,
    const unsigned short* __restrict__ Wf,   // [10][2][KF][4][64][8]
    const float* __restrict__ rbuf, float* __restrict__ h,
    int dec, const float* __restrict__ pW, const float* __restrict__ pb,
    float* __restrict__ go, float* __restrict__ dout)
{
  __shared__ alignas(16) unsigned short XA1f[KF*64*40];
  __shared__ alignas(16) unsigned short XA2f[KF*64*40];
  __shared__ float nvs[DD][64];
  int n0 = blockIdx.x*64;
  int tid = threadIdx.x;
  {
    int m = tid >> 2, ksub = tid & 3;
    int gm = n0 + m;
    float lsi = 1.f/(ls[gm] + ls[BNP+gm]);
    float xv;
    if (xmode == 0) { int b = gm/NN; int n = gm - b*NN; xv = (gm < BN) ? xsrc[(b*tlen+t)*NN + n] : 0.f; }
    else xv = xsrc[gm];
    unsigned int* X1 = (unsigned int*)XA1f;
    unsigned int* X2 = (unsigned int*)XA2f;
#pragma unroll 4
    for (int i = 0; i < 20; ++i) {
      int kk = ksub*2 + 8*i;
      float v0, v1;
      if (kk == 0)        v0 = xv;
      else if (kk <= 64)  v0 = zh[(size_t)(kk-1)*BNP + gm];
      else if (kk == 65)  v0 = 1.f;
      else if (kk <= 130) v0 = (axP[(size_t)(kk-66)*BNP + gm] + axP[(size_t)(65+kk-66)*BNP + gm]) * lsi;
      else v0 = 0.f;
      int k1 = kk + 1;
      if (k1 <= 64)       v1 = zh[(size_t)(k1-1)*BNP + gm];
      else if (k1 == 65)  v1 = 1.f;
      else if (k1 <= 130) v1 = (axP[(size_t)(k1-66)*BNP + gm] + axP[(size_t)(65+k1-66)*BNP + gm]) * lsi;
      else v1 = 0.f;
      unsigned int h0 = bf_hi(v0), h1 = bf_hi(v1);
      unsigned int l0 = bf_hi(v0 - bf_f(h0)), l1 = bf_hi(v1 - bf_f(h1));
      int kf = kk >> 5, kkl = kk & 31;
      int dw = (kf*64 + m)*20 + (kkl >> 1);
      X1[dw] = h0 | (h1 << 16);
      X2[dw] = l0 | (l1 << 16);
    }
  }
  for (int idx = tid; idx < DD*64; idx += 256)
    nvs[idx>>6][idx&63] = nv1T[(size_t)(idx>>6)*BNP + n0 + (idx&63)];
  __syncthreads();
  int w = tid >> 6, lane = tid & 63;
  int lm = lane & 15, quad = lane >> 4;
  int mp = w >> 1, np = w & 1;
  short8 A1[2][KF], A2[2][KF];
#pragma unroll
  for (int mt = 0; mt < 2; ++mt) {
    int mrow = mp*32 + mt*16 + lm;
#pragma unroll
    for (int kf = 0; kf < KF; ++kf) {
      A1[mt][kf] = *(const short8*)&XA1f[(kf*64 + mrow)*40 + quad*8];
      A2[mt][kf] = *(const short8*)&XA2f[(kf*64 + mrow)*40 + quad*8];
    }
  }
  f32x4 accO[2][2] = {};
  int ob0 = np*32 + lm;
#pragma unroll 2
  for (int d = 0; d < DD; ++d) {
    f32x4 td[2][2] = {};
#pragma unroll
    for (int ntl = 0; ntl < 2; ++ntl) {
      int ob = ob0 + ntl*16;
#pragma unroll
      for (int kf = 0; kf < KF; ++kf) {
        short8 Bh = *(const short8*)(Wf + ((((size_t)(d*2+0)*KF + kf)*4 + quad)*64 + ob)*8);
        short8 Bl = *(const short8*)(Wf + ((((size_t)(d*2+1)*KF + kf)*4 + quad)*64 + ob)*8);
#pragma unroll
        for (int mt = 0; mt < 2; ++mt) {
          td[mt][ntl] = __builtin_amdgcn_mfma_f32_16x16x32_bf16(A1[mt][kf], Bh, td[mt][ntl], 0,0,0);
          td[mt][ntl] = __builtin_amdgcn_mfma_f32_16x16x32_bf16(A1[mt][kf], Bl, td[mt][ntl], 0,0,0);
          td[mt][ntl] = __builtin_amdgcn_mfma_f32_16x16x32_bf16(A2[mt][kf], Bh, td[mt][ntl], 0,0,0);
        }
      }
    }
#pragma unroll
    for (int mt = 0; mt < 2; ++mt) {
      float4 nv4 = *(const float4*)&nvs[d][mp*32 + mt*16 + quad*4];
      const float* nvp = (const float*)&nv4;
#pragma unroll
      for (int ntl = 0; ntl < 2; ++ntl)
#pragma unroll
        for (int r = 0; r < 4; ++r)
          accO[mt][ntl][r] += nvp[r] * td[mt][ntl][r];
    }
  }
  float* CT = (float*)XA1f;   // [64][67] + PS at +64*67
  __syncthreads();
#pragma unroll
  for (int mt = 0; mt < 2; ++mt)
#pragma unroll
    for (int ntl = 0; ntl < 2; ++ntl)
#pragma unroll
      for (int r = 0; r < 4; ++r)
        CT[(mp*32 + mt*16 + quad*4 + r)*67 + np*32 + ntl*16 + lm] = accO[mt][ntl][r];
  __syncthreads();
  {
    int mm = tid & 63, og = tid >> 6;
    int gm = n0 + mm;
    float pp = 0.f;
    for (int j = 0; j < 16; ++j) {
      int o = og*16 + j;
      float hc = tanhf(CT[mm*67 + o]);
      float r = rbuf[(size_t)o*BNP + gm];
      float hv = h[(size_t)o*BNP + gm];
      float hn = r*hv + (1.f - r)*hc;
      h[(size_t)o*BNP + gm] = hn;
      if (dec) pp = fmaf(hn, pW[o], pp);
    }
    if (dec) {
      float* PS = CT + 64*67;
      __syncthreads();
      PS[mm*4 + og] = pp;
      __syncthreads();
      if (tid < 64 && gm < BN) {
        float s = pb[0] + PS[tid*4] + PS[tid*4+1] + PS[tid*4+2] + PS[tid*4+3];
        go[gm] = s;
        int b = gm/NN, n = gm - b*NN;
        dout[(b*HORZ + t)*NN + n] = s;
      }
    }
  }
}

extern "C" void kernel_launch(void* const* d_in, const int* in_sizes, int n_in,
                              void* d_out, int out_size, void* d_ws, size_t ws_size,
                              hipStream_t stream) {
  (void)in_sizes; (void)n_in; (void)out_size; (void)ws_size;
  const float* src_vals = (const float*)d_in[0];
  const float* node_emb = (const float*)d_in[1];
  const float* tid1 = (const float*)d_in[2];
  const float* tid2 = (const float*)d_in[3];
  const float* diw1 = (const float*)d_in[4];
  const float* diw2 = (const float*)d_in[5];
  const float* egW = (const float*)d_in[6];
  const float* egb = (const float*)d_in[7];
  const float* euW = (const float*)d_in[8];
  const float* eub = (const float*)d_in[9];
  const float* dgW = (const float*)d_in[10];
  const float* dgb = (const float*)d_in[11];
  const float* duW = (const float*)d_in[12];
  const float* dub = (const float*)d_in[13];
  const float* pW  = (const float*)d_in[14];
  const float* pb  = (const float*)d_in[15];
  const int* stid = (const int*)d_in[16];
  const int* sdiw = (const int*)d_in[17];
  const int* ttid = (const int*)d_in[18];
  const int* tdiw = (const int*)d_in[19];
  float* out = (float*)d_out;

  float* wp = (float*)d_ws;
  float* hbuf = wp; wp += (size_t)64*BNP;
  float* zh   = wp; wp += (size_t)64*BNP;
  float* rbuf = wp; wp += (size_t)64*BNP;
  float* axP  = wp; wp += (size_t)2*65*BNP;
  float* ls   = wp; wp += (size_t)2*BNP;
  float* nv1T = wp; wp += (size_t)DD*BNP;
  float* nv2T = wp; wp += (size_t)DD*BNP;
  float* go   = wp; wp += BN;
  unsigned short* egS = (unsigned short*)wp; wp += 204800;  // 10*2*5*4*128*8 shorts
  unsigned short* dgS = (unsigned short*)wp; wp += 204800;
  unsigned short* euS = (unsigned short*)wp; wp += 102400;  // 10*2*5*4*64*8 shorts
  unsigned short* duS = (unsigned short*)wp; wp += 102400;

  hipMemsetAsync(hbuf, 0, sizeof(float)*(size_t)64*BNP, stream);
  hipMemsetAsync(go, 0, sizeof(float)*BN, stream);

  wsplit_kernel<<<1600,256,0,stream>>>(egW, egb, 128, egS);
  wsplit_kernel<<<1600,256,0,stream>>>(dgW, dgb, 128, dgS);
  wsplit_kernel<<<800,256,0,stream>>>(euW, eub, 64, euS);
  wsplit_kernel<<<800,256,0,stream>>>(duW, dub, 64, duS);

  dim3 agrid(14, BB, 2);
  dim3 ggrid(442, 2);
  for (int t = 0; t < TSRC; ++t) {
    prep_kernel<<<111,256,0,stream>>>(tid1,tid2,diw1,diw2,node_emb,stid,sdiw,t,TSRC,nv1T,nv2T);
    attn_kernel<<<agrid,256,0,stream>>>(nv1T,nv2T,src_vals,0,t,TSRC,hbuf,axP,ls);
    gate_mfma<<<ggrid,256,0,stream>>>(src_vals,0,t,TSRC,hbuf,axP,ls,nv1T,egS,zh,rbuf);
    attn_kernel<<<agrid,256,0,stream>>>(nv1T,nv2T,src_vals,0,t,TSRC,zh,axP,ls);
    upd_mfma<<<442,256,0,stream>>>(src_vals,0,t,TSRC,zh,axP,ls,nv1T,euS,rbuf,hbuf,0,pW,pb,go,out);
  }
  for (int t = 0; t < HORZ; ++t) {
    prep_kernel<<<111,256,0,stream>>>(tid1,tid2,diw1,diw2,node_emb,ttid,tdiw,t,HORZ,nv1T,nv2T);
    attn_kernel<<<agrid,256,0,stream>>>(nv1T,nv2T,go,1,t,HORZ,hbuf,axP,ls);
    gate_mfma<<<ggrid,256,0,stream>>>(go,1,t,HORZ,hbuf,axP,ls,nv1T,dgS,zh,rbuf);
    attn_kernel<<<agrid,256,0,stream>>>(nv1T,nv2T,go,1,t,HORZ,zh,axP,ls);
    upd_mfma<<<442,256,0,stream>>>(go,1,t,HORZ,zh,axP,ls,nv1T,duS,rbuf,hbuf,1,pW,pb,go,out);
  }
}

// Round 10
// 7109.128 us; speedup vs baseline: 1.6358x; 1.3581x over previous
//
#include <hip/hip_runtime.h>

#define BB 32
#define TSRC 12
#define HORZ 12
#define NN 883
#define DD 10
#define HH 64
#define BN (BB*NN)     // 28256
#define BNP 28288      // 64-aligned stride
#define KF 5           // gate/upd MFMA K-frags: K=160. k-map: 0=x, 1..64=h, 65=bias, 66..130=axT, 131..159=0

typedef __attribute__((ext_vector_type(8))) short short8;
typedef __attribute__((ext_vector_type(4))) float f32x4;

static __device__ __forceinline__ float sigmf(float x) { return 1.f/(1.f + __expf(-x)); }
static __device__ __forceinline__ float tanh_fast(float x) {
  float e = __expf(2.f*x);
  return (e - 1.f) / (e + 1.f);
}
static __device__ __forceinline__ unsigned int bf_hi(float f) {
  unsigned int u = __float_as_uint(f);
  return (u + 0x7fffu + ((u >> 16) & 1u)) >> 16;
}
static __device__ __forceinline__ float bf_f(unsigned int h) {
  return __uint_as_float(h << 16);
}

// ---------------- prep: nv1T/nv2T [10][BNP] ----------------
__global__ __launch_bounds__(256) void prep_kernel(
    const float* __restrict__ tidE1, const float* __restrict__ tidE2,
    const float* __restrict__ diwE1, const float* __restrict__ diwE2,
    const float* __restrict__ nodeE,
    const int* __restrict__ tididx, const int* __restrict__ diwidx,
    int t, int tlen,
    float* __restrict__ nv1T, float* __restrict__ nv2T)
{
  int i = blockIdx.x*256 + threadIdx.x;
  if (i >= BN) return;
  int b = i / NN, n = i - b*NN;
  int gi = (b*tlen + t)*NN + n;
  int ti = tididx[gi]*DD, di = diwidx[gi]*DD;
  int nE = n*DD;
#pragma unroll
  for (int d = 0; d < DD; ++d) {
    float E = nodeE[nE+d];
    nv1T[d*BNP+i] = tanh_fast(E * (tidE1[ti+d] * diwE1[di+d]));
    nv2T[d*BNP+i] = tanh_fast(E * (tidE2[ti+d] * diwE2[di+d]));
  }
}

// ------- wsplit: W -> B-fragment-ordered split-bf16 Wf[d][hl][kf][quad][NO][8] -------
__global__ __launch_bounds__(256) void wsplit_kernel(
    const float* __restrict__ W, const float* __restrict__ bias,
    int NO, unsigned short* __restrict__ Wf)
{
  int i = blockIdx.x*256 + threadIdx.x;
  int total = DD*2*KF*4*NO*8;
  if (i >= total) return;
  int j = i & 7; int r = i >> 3;
  int o = r % NO; r /= NO;
  int quad = r & 3; r >>= 2;
  int kf = r % KF; r /= KF;
  int hl = r & 1; int d = r >> 1;
  int kk = kf*32 + quad*8 + j;
  float v = 0.f;
  if (kk <= 64)       v = W[(size_t)(d*130 + kk)*NO + o];
  else if (kk == 65)  v = bias[d*NO + o];
  else if (kk <= 130) v = W[(size_t)(d*130 + kk - 1)*NO + o];
  unsigned int hi = bf_hi(v);
  Wf[i] = (hl == 0) ? (unsigned short)hi : (unsigned short)bf_hi(v - bf_f(hi));
}

// ------- attn: softmax(relu(nv1 nv2^T)) @ [x|h] -> axT [65][BNP] normalized. grid (14,32) -------
// MFMA AV: P split-bf16 in A-frag layout, X^T split-bf16 in B-frag layout.
__global__ __launch_bounds__(256,3) void attn_kernel(
    const float* __restrict__ nv1T, const float* __restrict__ nv2T,
    const float* __restrict__ xsrc, int xmode, int t, int tlen,
    const float* __restrict__ hsrc,
    float* __restrict__ axT)
{
  __shared__ float nv1s[DD][64];
  __shared__ float nv2s[DD][64];
  __shared__ alignas(16) unsigned short XT[2][64][72];  // [hl][c][m] (B-frag: rows=c, k=m)
  __shared__ alignas(16) unsigned short PT[2][64][72];  // [hl][r][m] (A-frag: rows=r, k=m)
  __shared__ float xcol[64];
  __shared__ float linv[64];
  int b = blockIdx.y;
  int r0 = blockIdx.x*64;
  int tid = threadIdx.x;
  int rg = tid >> 4, cg = tid & 15;
  int base = b*NN;
  int lane = tid & 63, lm = lane & 15, quad = lane >> 4;
  int w = tid >> 6, mp = w >> 1, np = w & 1;

  for (int idx = tid; idx < DD*64; idx += 256) {
    int d = idx >> 6, r = idx & 63;
    nv1s[d][r] = (r0 + r < NN) ? nv1T[d*BNP + base + r0 + r] : 0.f;
  }

  f32x4 accv[2][2] = {};
  float acclp[4] = {}, acc5p[4] = {};

  for (int m0 = 0; m0 < NN; m0 += 64) {
    __syncthreads();
    for (int idx = tid; idx < DD*64; idx += 256) {
      int d = idx >> 6, m = idx & 63;
      nv2s[d][m] = (m0 + m < NN) ? nv2T[d*BNP + base + m0 + m] : 0.f;
    }
    // XT staging: lane m = tid&63 (coalesced along m), cb = tid>>6 covers 16 c's
    {
      int m = tid & 63, cb = tid >> 6;
      int mm = m0 + m;
      bool ok = mm < NN;
      float xv = 0.f;
      if (cb == 0 && ok) xv = (xmode == 0) ? xsrc[(b*tlen+t)*NN + mm] : xsrc[base + mm];
#pragma unroll 4
      for (int i = 0; i < 16; ++i) {
        int c = cb*16 + i;
        float v = (c == 0) ? xv : hsrc[(size_t)(c-1)*BNP + base + mm];  // overrun stays in padded buffer; killed by p=0
        unsigned int hi = bf_hi(v);
        XT[0][c][m] = (unsigned short)hi;
        XT[1][c][m] = (unsigned short)bf_hi(v - bf_f(hi));
      }
      if (tid < 64) xcol[tid] = (m0 + tid < NN) ? hsrc[(size_t)63*BNP + base + m0 + tid] : 0.f;
    }
    __syncthreads();
    // QK^T (VALU, K=10)
    float s[4][4] = {};
#pragma unroll
    for (int d = 0; d < DD; ++d) {
      float4 a4 = *(const float4*)&nv1s[d][rg*4];
      float4 c4 = *(const float4*)&nv2s[d][cg*4];
      const float* ap = (const float*)&a4;
      const float* cp = (const float*)&c4;
#pragma unroll
      for (int j = 0; j < 4; ++j)
#pragma unroll
        for (int jj = 0; jj < 4; ++jj)
          s[j][jj] += ap[j]*cp[jj];
    }
    // exp + folds, pack P split-bf16 into PT (A-frag layout)
    int mvlim = NN - m0;
    float ev[4][4];
#pragma unroll
    for (int jj = 0; jj < 4; ++jj) {
      int m = cg*4 + jj;
      float xm = xcol[m];
      bool okm = m < mvlim;
#pragma unroll
      for (int j = 0; j < 4; ++j) {
        float e = okm ? __expf(fmaxf(s[j][jj], 0.f)) : 0.f;
        ev[j][jj] = e;
        acclp[j] += e;
        acc5p[j] = fmaf(e, xm, acc5p[j]);
      }
    }
    {
      unsigned int* P1 = (unsigned int*)&PT[0][0][0];
      unsigned int* P2 = (unsigned int*)&PT[1][0][0];
#pragma unroll
      for (int j = 0; j < 4; ++j) {
        int r = rg*4 + j;
        unsigned int h0 = bf_hi(ev[j][0]), h1 = bf_hi(ev[j][1]), h2 = bf_hi(ev[j][2]), h3 = bf_hi(ev[j][3]);
        unsigned int l0 = bf_hi(ev[j][0]-bf_f(h0)), l1 = bf_hi(ev[j][1]-bf_f(h1));
        unsigned int l2 = bf_hi(ev[j][2]-bf_f(h2)), l3 = bf_hi(ev[j][3]-bf_f(h3));
        int dw = r*36 + cg*2;
        P1[dw] = h0 | (h1 << 16); P1[dw+1] = h2 | (h3 << 16);
        P2[dw] = l0 | (l1 << 16); P2[dw+1] = l2 | (l3 << 16);
      }
    }
    __syncthreads();
    // AV via MFMA: wave (mp,np) does M-tiles mp*2+{0,1}, N-tiles np*2+{0,1}
    {
      short8 Aa[2][2], Ab[2][2], Ba[2][2], Bb[2][2];
#pragma unroll
      for (int mt = 0; mt < 2; ++mt) {
        int r = mp*32 + mt*16 + lm;
#pragma unroll
        for (int kf = 0; kf < 2; ++kf) {
          Aa[mt][kf] = *(const short8*)&PT[0][r][quad*8 + kf*32];
          Ab[mt][kf] = *(const short8*)&PT[1][r][quad*8 + kf*32];
        }
      }
#pragma unroll
      for (int ntl = 0; ntl < 2; ++ntl) {
        int c = np*32 + ntl*16 + lm;
#pragma unroll
        for (int kf = 0; kf < 2; ++kf) {
          Ba[ntl][kf] = *(const short8*)&XT[0][c][quad*8 + kf*32];
          Bb[ntl][kf] = *(const short8*)&XT[1][c][quad*8 + kf*32];
        }
      }
#pragma unroll
      for (int kf = 0; kf < 2; ++kf)
#pragma unroll
        for (int mt = 0; mt < 2; ++mt)
#pragma unroll
          for (int ntl = 0; ntl < 2; ++ntl) {
            accv[mt][ntl] = __builtin_amdgcn_mfma_f32_16x16x32_bf16(Aa[mt][kf], Ba[ntl][kf], accv[mt][ntl], 0,0,0);
            accv[mt][ntl] = __builtin_amdgcn_mfma_f32_16x16x32_bf16(Aa[mt][kf], Bb[ntl][kf], accv[mt][ntl], 0,0,0);
            accv[mt][ntl] = __builtin_amdgcn_mfma_f32_16x16x32_bf16(Ab[mt][kf], Ba[ntl][kf], accv[mt][ntl], 0,0,0);
          }
    }
  }
  // reduce row-sums / x-col over cg
#pragma unroll
  for (int off = 1; off <= 8; off <<= 1)
#pragma unroll
    for (int j = 0; j < 4; ++j) {
      acclp[j] += __shfl_xor(acclp[j], off, 64);
      acc5p[j] += __shfl_xor(acc5p[j], off, 64);
    }
  __syncthreads();
  if (cg == 0) {
#pragma unroll
    for (int j = 0; j < 4; ++j) {
      float li = 1.f / acclp[j];
      linv[rg*4 + j] = li;
      int r = r0 + rg*4 + j;
      if (r < NN) axT[(size_t)64*BNP + base + r] = acc5p[j]*li;
    }
  }
  __syncthreads();
  // epilogue: normalize + transpose through LDS (stride 69: conflict-free column reads)
  float* CT = (float*)&PT[0][0][0];   // [64][69]
#pragma unroll
  for (int mt = 0; mt < 2; ++mt) {
    float4 lv = *(const float4*)&linv[mp*32 + mt*16 + quad*4];
    const float* lvp = (const float*)&lv;
#pragma unroll
    for (int ntl = 0; ntl < 2; ++ntl) {
      int c = np*32 + ntl*16 + lm;
#pragma unroll
      for (int r4 = 0; r4 < 4; ++r4)
        CT[(mp*32 + mt*16 + quad*4 + r4)*69 + c] = accv[mt][ntl][r4]*lvp[r4];
    }
  }
  __syncthreads();
  {
    int r = tid & 63, cb = tid >> 6;
    bool ok = (r0 + r) < NN;
    int gr = base + r0 + r;
#pragma unroll 4
    for (int i = 0; i < 16; ++i) {
      int c = cb*16 + i;
      if (ok) axT[(size_t)c*BNP + gr] = CT[r*69 + c];
    }
  }
}

// ======= MFMA GEMM kernels (unchanged core from R9, axT single-row input) =======

// ------- gate: grid (442, 2=co-half). zr = sigmoid -------
__global__ __launch_bounds__(256,2) void gate_mfma(
    const float* __restrict__ xsrc, int xmode, int t, int tlen,
    const float* __restrict__ h,
    const float* __restrict__ axT,
    const float* __restrict__ nv1T,
    const unsigned short* __restrict__ Wf,   // [10][2][KF][4][128][8]
    float* __restrict__ zh, float* __restrict__ rbuf)
{
  __shared__ alignas(16) unsigned short XA1f[KF*64*40];
  __shared__ alignas(16) unsigned short XA2f[KF*64*40];
  __shared__ float nvs[DD][64];
  int n0 = blockIdx.x*64, co0 = blockIdx.y*64;
  int tid = threadIdx.x;
  {
    int m = tid >> 2, ksub = tid & 3;
    int gm = n0 + m;
    float xv;
    if (xmode == 0) { int b = gm/NN; int n = gm - b*NN; xv = (gm < BN) ? xsrc[(b*tlen+t)*NN + n] : 0.f; }
    else xv = xsrc[gm];
    unsigned int* X1 = (unsigned int*)XA1f;
    unsigned int* X2 = (unsigned int*)XA2f;
#pragma unroll 4
    for (int i = 0; i < 20; ++i) {
      int kk = ksub*2 + 8*i;
      float v0, v1;
      if (kk == 0)        v0 = xv;
      else if (kk <= 64)  v0 = h[(size_t)(kk-1)*BNP + gm];
      else if (kk == 65)  v0 = 1.f;
      else if (kk <= 130) v0 = axT[(size_t)(kk-66)*BNP + gm];
      else v0 = 0.f;
      int k1 = kk + 1;
      if (k1 <= 64)       v1 = h[(size_t)(k1-1)*BNP + gm];
      else if (k1 == 65)  v1 = 1.f;
      else if (k1 <= 130) v1 = axT[(size_t)(k1-66)*BNP + gm];
      else v1 = 0.f;
      unsigned int h0 = bf_hi(v0), h1 = bf_hi(v1);
      unsigned int l0 = bf_hi(v0 - bf_f(h0)), l1 = bf_hi(v1 - bf_f(h1));
      int kf = kk >> 5, kkl = kk & 31;
      int dw = (kf*64 + m)*20 + (kkl >> 1);
      X1[dw] = h0 | (h1 << 16);
      X2[dw] = l0 | (l1 << 16);
    }
  }
  for (int idx = tid; idx < DD*64; idx += 256)
    nvs[idx>>6][idx&63] = nv1T[(size_t)(idx>>6)*BNP + n0 + (idx&63)];
  __syncthreads();
  int w = tid >> 6, lane = tid & 63;
  int lm = lane & 15, quad = lane >> 4;
  int mp = w >> 1, np = w & 1;
  short8 A1[2][KF], A2[2][KF];
#pragma unroll
  for (int mt = 0; mt < 2; ++mt) {
    int mrow = mp*32 + mt*16 + lm;
#pragma unroll
    for (int kf = 0; kf < KF; ++kf) {
      A1[mt][kf] = *(const short8*)&XA1f[(kf*64 + mrow)*40 + quad*8];
      A2[mt][kf] = *(const short8*)&XA2f[(kf*64 + mrow)*40 + quad*8];
    }
  }
  f32x4 accO[2][2] = {};
  int ob0 = co0 + np*32 + lm;
#pragma unroll 2
  for (int d = 0; d < DD; ++d) {
    f32x4 td[2][2] = {};
#pragma unroll
    for (int ntl = 0; ntl < 2; ++ntl) {
      int ob = ob0 + ntl*16;
#pragma unroll
      for (int kf = 0; kf < KF; ++kf) {
        short8 Bh = *(const short8*)(Wf + ((((size_t)(d*2+0)*KF + kf)*4 + quad)*128 + ob)*8);
        short8 Bl = *(const short8*)(Wf + ((((size_t)(d*2+1)*KF + kf)*4 + quad)*128 + ob)*8);
#pragma unroll
        for (int mt = 0; mt < 2; ++mt) {
          td[mt][ntl] = __builtin_amdgcn_mfma_f32_16x16x32_bf16(A1[mt][kf], Bh, td[mt][ntl], 0,0,0);
          td[mt][ntl] = __builtin_amdgcn_mfma_f32_16x16x32_bf16(A1[mt][kf], Bl, td[mt][ntl], 0,0,0);
          td[mt][ntl] = __builtin_amdgcn_mfma_f32_16x16x32_bf16(A2[mt][kf], Bh, td[mt][ntl], 0,0,0);
        }
      }
    }
#pragma unroll
    for (int mt = 0; mt < 2; ++mt) {
      float4 nv4 = *(const float4*)&nvs[d][mp*32 + mt*16 + quad*4];
      const float* nvp = (const float*)&nv4;
#pragma unroll
      for (int ntl = 0; ntl < 2; ++ntl)
#pragma unroll
        for (int r = 0; r < 4; ++r)
          accO[mt][ntl][r] += nvp[r] * td[mt][ntl][r];
    }
  }
  float* CT = (float*)XA1f;   // [64][67]
  __syncthreads();
#pragma unroll
  for (int mt = 0; mt < 2; ++mt)
#pragma unroll
    for (int ntl = 0; ntl < 2; ++ntl)
#pragma unroll
      for (int r = 0; r < 4; ++r)
        CT[(mp*32 + mt*16 + quad*4 + r)*67 + np*32 + ntl*16 + lm] = accO[mt][ntl][r];
  __syncthreads();
  {
    int mm = tid & 63, og = tid >> 6;
    int gm = n0 + mm;
    if (co0 == 0) {
      for (int j = 0; j < 16; ++j) {
        int o = og*16 + j;
        float z = sigmf(CT[mm*67 + o]);
        zh[(size_t)o*BNP + gm] = z * h[(size_t)o*BNP + gm];
      }
    } else {
      for (int j = 0; j < 16; ++j) {
        int o = og*16 + j;
        rbuf[(size_t)o*BNP + gm] = sigmf(CT[mm*67 + o]);
      }
    }
  }
}

// ------- upd: grid (442). h = r*h+(1-r)*tanh; dec: fused proj -------
__global__ __launch_bounds__(256,2) void upd_mfma(
    const float* __restrict__ xsrc, int xmode, int t, int tlen,
    const float* __restrict__ zh,
    const float* __restrict__ axT,
    const float* __restrict__ nv1T,
    const unsigned short* __restrict__ Wf,   // [10][2][KF][4][64][8]
    const float* __restrict__ rbuf, float* __restrict__ h,
    int dec, const float* __restrict__ pW, const float* __restrict__ pb,
    float* __restrict__ go, float* __restrict__ dout)
{
  __shared__ alignas(16) unsigned short XA1f[KF*64*40];
  __shared__ alignas(16) unsigned short XA2f[KF*64*40];
  __shared__ float nvs[DD][64];
  int n0 = blockIdx.x*64;
  int tid = threadIdx.x;
  {
    int m = tid >> 2, ksub = tid & 3;
    int gm = n0 + m;
    float xv;
    if (xmode == 0) { int b = gm/NN; int n = gm - b*NN; xv = (gm < BN) ? xsrc[(b*tlen+t)*NN + n] : 0.f; }
    else xv = xsrc[gm];
    unsigned int* X1 = (unsigned int*)XA1f;
    unsigned int* X2 = (unsigned int*)XA2f;
#pragma unroll 4
    for (int i = 0; i < 20; ++i) {
      int kk = ksub*2 + 8*i;
      float v0, v1;
      if (kk == 0)        v0 = xv;
      else if (kk <= 64)  v0 = zh[(size_t)(kk-1)*BNP + gm];
      else if (kk == 65)  v0 = 1.f;
      else if (kk <= 130) v0 = axT[(size_t)(kk-66)*BNP + gm];
      else v0 = 0.f;
      int k1 = kk + 1;
      if (k1 <= 64)       v1 = zh[(size_t)(k1-1)*BNP + gm];
      else if (k1 == 65)  v1 = 1.f;
      else if (k1 <= 130) v1 = axT[(size_t)(k1-66)*BNP + gm];
      else v1 = 0.f;
      unsigned int h0 = bf_hi(v0), h1 = bf_hi(v1);
      unsigned int l0 = bf_hi(v0 - bf_f(h0)), l1 = bf_hi(v1 - bf_f(h1));
      int kf = kk >> 5, kkl = kk & 31;
      int dw = (kf*64 + m)*20 + (kkl >> 1);
      X1[dw] = h0 | (h1 << 16);
      X2[dw] = l0 | (l1 << 16);
    }
  }
  for (int idx = tid; idx < DD*64; idx += 256)
    nvs[idx>>6][idx&63] = nv1T[(size_t)(idx>>6)*BNP + n0 + (idx&63)];
  __syncthreads();
  int w = tid >> 6, lane = tid & 63;
  int lm = lane & 15, quad = lane >> 4;
  int mp = w >> 1, np = w & 1;
  short8 A1[2][KF], A2[2][KF];
#pragma unroll
  for (int mt = 0; mt < 2; ++mt) {
    int mrow = mp*32 + mt*16 + lm;
#pragma unroll
    for (int kf = 0; kf < KF; ++kf) {
      A1[mt][kf] = *(const short8*)&XA1f[(kf*64 + mrow)*40 + quad*8];
      A2[mt][kf] = *(const short8*)&XA2f[(kf*64 + mrow)*40 + quad*8];
    }
  }
  f32x4 accO[2][2] = {};
  int ob0 = np*32 + lm;
#pragma unroll 2
  for (int d = 0; d < DD; ++d) {
    f32x4 td[2][2] = {};
#pragma unroll
    for (int ntl = 0; ntl < 2; ++ntl) {
      int ob = ob0 + ntl*16;
#pragma unroll
      for (int kf = 0; kf < KF; ++kf) {
        short8 Bh = *(const short8*)(Wf + ((((size_t)(d*2+0)*KF + kf)*4 + quad)*64 + ob)*8);
        short8 Bl = *(const short8*)(Wf + ((((size_t)(d*2+1)*KF + kf)*4 + quad)*64 + ob)*8);
#pragma unroll
        for (int mt = 0; mt < 2; ++mt) {
          td[mt][ntl] = __builtin_amdgcn_mfma_f32_16x16x32_bf16(A1[mt][kf], Bh, td[mt][ntl], 0,0,0);
          td[mt][ntl] = __builtin_amdgcn_mfma_f32_16x16x32_bf16(A1[mt][kf], Bl, td[mt][ntl], 0,0,0);
          td[mt][ntl] = __builtin_amdgcn_mfma_f32_16x16x32_bf16(A2[mt][kf], Bh, td[mt][ntl], 0,0,0);
        }
      }
    }
#pragma unroll
    for (int mt = 0; mt < 2; ++mt) {
      float4 nv4 = *(const float4*)&nvs[d][mp*32 + mt*16 + quad*4];
      const float* nvp = (const float*)&nv4;
#pragma unroll
      for (int ntl = 0; ntl < 2; ++ntl)
#pragma unroll
        for (int r = 0; r < 4; ++r)
          accO[mt][ntl][r] += nvp[r] * td[mt][ntl][r];
    }
  }
  float* CT = (float*)XA1f;   // [64][67] + PS at +64*67
  __syncthreads();
#pragma unroll
  for (int mt = 0; mt < 2; ++mt)
#pragma unroll
    for (int ntl = 0; ntl < 2; ++ntl)
#pragma unroll
      for (int r = 0; r < 4; ++r)
        CT[(mp*32 + mt*16 + quad*4 + r)*67 + np*32 + ntl*16 + lm] = accO[mt][ntl][r];
  __syncthreads();
  {
    int mm = tid & 63, og = tid >> 6;
    int gm = n0 + mm;
    float pp = 0.f;
    for (int j = 0; j < 16; ++j) {
      int o = og*16 + j;
      float hc = tanhf(CT[mm*67 + o]);
      float r = rbuf[(size_t)o*BNP + gm];
      float hv = h[(size_t)o*BNP + gm];
      float hn = r*hv + (1.f - r)*hc;
      h[(size_t)o*BNP + gm] = hn;
      if (dec) pp = fmaf(hn, pW[o], pp);
    }
    if (dec) {
      float* PS = CT + 64*67;
      __syncthreads();
      PS[mm*4 + og] = pp;
      __syncthreads();
      if (tid < 64 && gm < BN) {
        float s = pb[0] + PS[tid*4] + PS[tid*4+1] + PS[tid*4+2] + PS[tid*4+3];
        go[gm] = s;
        int b = gm/NN, n = gm - b*NN;
        dout[(b*HORZ + t)*NN + n] = s;
      }
    }
  }
}

extern "C" void kernel_launch(void* const* d_in, const int* in_sizes, int n_in,
                              void* d_out, int out_size, void* d_ws, size_t ws_size,
                              hipStream_t stream) {
  (void)in_sizes; (void)n_in; (void)out_size; (void)ws_size;
  const float* src_vals = (const float*)d_in[0];
  const float* node_emb = (const float*)d_in[1];
  const float* tid1 = (const float*)d_in[2];
  const float* tid2 = (const float*)d_in[3];
  const float* diw1 = (const float*)d_in[4];
  const float* diw2 = (const float*)d_in[5];
  const float* egW = (const float*)d_in[6];
  const float* egb = (const float*)d_in[7];
  const float* euW = (const float*)d_in[8];
  const float* eub = (const float*)d_in[9];
  const float* dgW = (const float*)d_in[10];
  const float* dgb = (const float*)d_in[11];
  const float* duW = (const float*)d_in[12];
  const float* dub = (const float*)d_in[13];
  const float* pW  = (const float*)d_in[14];
  const float* pb  = (const float*)d_in[15];
  const int* stid = (const int*)d_in[16];
  const int* sdiw = (const int*)d_in[17];
  const int* ttid = (const int*)d_in[18];
  const int* tdiw = (const int*)d_in[19];
  float* out = (float*)d_out;

  float* wp = (float*)d_ws;
  float* hbuf = wp; wp += (size_t)64*BNP;
  float* zh   = wp; wp += (size_t)64*BNP;
  float* rbuf = wp; wp += (size_t)64*BNP;
  float* axT  = wp; wp += (size_t)65*BNP;
  float* nv1T = wp; wp += (size_t)DD*BNP;
  float* nv2T = wp; wp += (size_t)DD*BNP;
  float* go   = wp; wp += BN + 64;
  unsigned short* egS = (unsigned short*)wp; wp += 204800;  // 10*2*5*4*128*8 shorts
  unsigned short* dgS = (unsigned short*)wp; wp += 204800;
  unsigned short* euS = (unsigned short*)wp; wp += 102400;  // 10*2*5*4*64*8 shorts
  unsigned short* duS = (unsigned short*)wp; wp += 102400;

  hipMemsetAsync(hbuf, 0, sizeof(float)*(size_t)64*BNP, stream);
  hipMemsetAsync(go, 0, sizeof(float)*(BN+64), stream);

  wsplit_kernel<<<1600,256,0,stream>>>(egW, egb, 128, egS);
  wsplit_kernel<<<1600,256,0,stream>>>(dgW, dgb, 128, dgS);
  wsplit_kernel<<<800,256,0,stream>>>(euW, eub, 64, euS);
  wsplit_kernel<<<800,256,0,stream>>>(duW, dub, 64, duS);

  dim3 agrid(14, BB);
  dim3 ggrid(442, 2);
  for (int t = 0; t < TSRC; ++t) {
    prep_kernel<<<111,256,0,stream>>>(tid1,tid2,diw1,diw2,node_emb,stid,sdiw,t,TSRC,nv1T,nv2T);
    attn_kernel<<<agrid,256,0,stream>>>(nv1T,nv2T,src_vals,0,t,TSRC,hbuf,axT);
    gate_mfma<<<ggrid,256,0,stream>>>(src_vals,0,t,TSRC,hbuf,axT,nv1T,egS,zh,rbuf);
    attn_kernel<<<agrid,256,0,stream>>>(nv1T,nv2T,src_vals,0,t,TSRC,zh,axT);
    upd_mfma<<<442,256,0,stream>>>(src_vals,0,t,TSRC,zh,axT,nv1T,euS,rbuf,hbuf,0,pW,pb,go,out);
  }
  for (int t = 0; t < HORZ; ++t) {
    prep_kernel<<<111,256,0,stream>>>(tid1,tid2,diw1,diw2,node_emb,ttid,tdiw,t,HORZ,nv1T,nv2T);
    attn_kernel<<<agrid,256,0,stream>>>(nv1T,nv2T,go,1,t,HORZ,hbuf,axT);
    gate_mfma<<<ggrid,256,0,stream>>>(go,1,t,HORZ,hbuf,axT,nv1T,dgS,zh,rbuf);
    attn_kernel<<<agrid,256,0,stream>>>(nv1T,nv2T,go,1,t,HORZ,zh,axT);
    upd_mfma<<<442,256,0,stream>>>(go,1,t,HORZ,zh,axT,nv1T,duS,rbuf,hbuf,1,pW,pb,go,out);
  }
}